// Round 4
// baseline (21.405 us; speedup 1.0000x reference)
//
#include <hip/hip_runtime.h>
#include <math.h>

// Reranker tie-aware RankNet loss — R4 (fused single kernel).
// B=4096 rows, n=64. One 64-lane wave per row; 256 blocks x 1024 threads.
//   - group-end e via one __ballot + ctz
//   - mask (y_true[a]>y_true[b]) == (b > e(a));  cnt = 63-e analytic
//   - softplus in base-2: ln2 * (max(t,0) + log2(1+2^-|t|)), t=(pb-pa)*log2e
//     -> exactly one v_exp_f32 + one v_log_f32 per pair, ln2 hoisted to end
//   - branch-free 4-chain accumulation (no switch; unroll-friendly)
//   - single-kernel finalize: ticket atomic (agent scope); the block that
//     draws residue nb-1 reduces all partials in FIXED order -> deterministic.

#define N 64
#define RPB 16                 // rows (waves) per 1024-thread block
#define LOG2E 1.4426950408889634f
#define LN2   0.6931471805599453f

__device__ __forceinline__ float readlane_f(float v, int srclane) {
    return __int_as_float(__builtin_amdgcn_readlane(__float_as_int(v), srclane));
}

__device__ __forceinline__ float pair_term(float predl2, int e, int b) {
    float pbl2 = readlane_f(predl2, b);      // SGPR broadcast of lane b
    float t  = pbl2 - predl2;                // (pred_b - pred_a) * log2(e)
    float g  = exp2f(-fabsf(t));             // v_exp_f32 (input mods fold)
    float l  = log2f(1.0f + g);              // v_log_f32
    float sp = fmaxf(t, 0.0f) + l;           // softplus(z) / ln2
    return (b > e) ? sp : 0.0f;              // v_cmp + v_cndmask
}

__global__ __launch_bounds__(1024) void rank_loss_fused(
    const float* __restrict__ logits, const int* __restrict__ kd,
    float* __restrict__ out, float* __restrict__ partials,
    unsigned* __restrict__ ticket, int B, int nb)
{
    const int lane = threadIdx.x & 63;
    const int wave = threadIdx.x >> 6;
    const int row  = blockIdx.x * RPB + wave;

    float acc0 = 0.f, acc1 = 0.f, acc2 = 0.f, acc3 = 0.f;
    float cnt = 0.f;

    if (row < B) {
        const int base = row * N + lane;
        const int   k      = kd[base];
        const float predl2 = logits[base] * LOG2E;

        // group-end lane e: smallest j >= lane with (j==63 or k[j]!=k[j+1])
        const int knext = __shfl_down(k, 1);
        unsigned long long endm = __ballot(lane == 63 || k != knext);
        const int e = lane + __builtin_ctzll(endm >> lane);  // bit63 always set
        cnt = (float)(63 - e);

        #pragma unroll
        for (int b = 0; b < N; b += 4) {     // 4 independent chains, no branches
            acc0 += pair_term(predl2, e, b + 0);
            acc1 += pair_term(predl2, e, b + 1);
            acc2 += pair_term(predl2, e, b + 2);
            acc3 += pair_term(predl2, e, b + 3);
        }
    }

    float psum = (acc0 + acc1) + (acc2 + acc3);
    #pragma unroll
    for (int off = 32; off; off >>= 1) {
        psum += __shfl_down(psum, off);
        cnt  += __shfl_down(cnt,  off);
    }

    __shared__ float ssum[RPB], scnt[RPB];
    __shared__ int lastFlag;
    if (lane == 0) { ssum[wave] = psum; scnt[wave] = cnt; }
    __syncthreads();

    if (threadIdx.x == 0) {
        float s = 0.f, c = 0.f;
        #pragma unroll
        for (int w = 0; w < RPB; ++w) { s += ssum[w]; c += scnt[w]; }
        __hip_atomic_store(&partials[2 * blockIdx.x + 0], s,
                           __ATOMIC_RELAXED, __HIP_MEMORY_SCOPE_AGENT);
        __hip_atomic_store(&partials[2 * blockIdx.x + 1], c,
                           __ATOMIC_RELAXED, __HIP_MEMORY_SCOPE_AGENT);
        unsigned t = __hip_atomic_fetch_add(ticket, 1u,
                           __ATOMIC_ACQ_REL, __HIP_MEMORY_SCOPE_AGENT);
        // any nb consecutive tickets contain exactly one == nb-1 (mod nb):
        // works regardless of the poisoned starting value of *ticket.
        lastFlag = ((t % (unsigned)nb) == (unsigned)(nb - 1)) ? 1 : 0;
    }
    __syncthreads();

    if (lastFlag && wave == 0) {             // one wave reduces, fixed order
        float s = 0.f, c = 0.f;
        for (int i = lane; i < nb; i += 64) {
            s += __hip_atomic_load(&partials[2 * i + 0],
                                   __ATOMIC_RELAXED, __HIP_MEMORY_SCOPE_AGENT);
            c += __hip_atomic_load(&partials[2 * i + 1],
                                   __ATOMIC_RELAXED, __HIP_MEMORY_SCOPE_AGENT);
        }
        #pragma unroll
        for (int off = 32; off; off >>= 1) {
            s += __shfl_down(s, off);
            c += __shfl_down(c, off);
        }
        if (lane == 0) out[0] = s * LN2 / c;
    }
}

extern "C" void kernel_launch(void* const* d_in, const int* in_sizes, int n_in,
                              void* d_out, int out_size, void* d_ws, size_t ws_size,
                              hipStream_t stream) {
    const float* logits = (const float*)d_in[0];
    const int*   kd     = (const int*)d_in[1];
    float*       out    = (float*)d_out;
    const int B  = in_sizes[1] / N;                  // 4096
    const int nb = (B + RPB - 1) / RPB;              // 256

    float*    partials = (float*)d_ws;               // 2*nb floats
    unsigned* ticket   = (unsigned*)((char*)d_ws + 4096);

    rank_loss_fused<<<nb, RPB * 64, 0, stream>>>(logits, kd, out, partials,
                                                 ticket, B, nb);
}

// Round 5
// 15.015 us; speedup vs baseline: 1.4256x; 1.4256x over previous
//
#include <hip/hip_runtime.h>
#include <math.h>

// Reranker tie-aware RankNet loss — R5.
// B=4096 rows, n=64. One 64-lane wave per row (4096 waves, 1024 blocks x 256).
//   - group-end e via one __ballot + ctz;  mask (b > e);  cnt = 63-e analytic
//   - softplus in base-2: ln2*(max(t,0)+log2(1+2^-|t|)), t=(pb-pa)*log2e
//   - RAW trans builtins: __builtin_amdgcn_exp2f / logf  (single v_exp/v_log)
//   - rolled outer loop (#pragma unroll 1), 8 branch-free terms per iteration
//     into 8 named accumulators: bounded VGPR, 8-deep ILP window, no switch.
// Two-stage deterministic reduction: per-block partials -> finalize kernel.

#define N 64
#define WPB 4
#define LN2 0.6931471805599453f
#define LOG2E 1.4426950408889634f

__device__ __forceinline__ float readlane_f(float v, int srclane) {
    return __int_as_float(__builtin_amdgcn_readlane(__float_as_int(v), srclane));
}

#define TERM(i, acc) do {                                          \
    float t_  = readlane_f(predl2, bb + (i)) - predl2;             \
    float g_  = __builtin_amdgcn_exp2f(-fabsf(t_));                \
    float l_  = __builtin_amdgcn_logf(1.0f + g_);                  \
    float sp_ = fmaxf(t_, 0.0f) + l_;                              \
    acc += ((bb + (i)) > e) ? sp_ : 0.0f;                          \
} while (0)

__global__ __launch_bounds__(256) void rank_loss_partial(
    const float* __restrict__ logits, const int* __restrict__ kd,
    float2* __restrict__ partials, int B)
{
    const int lane = threadIdx.x & 63;
    const int wave = threadIdx.x >> 6;
    const int row  = blockIdx.x * WPB + wave;

    float a0=0.f,a1=0.f,a2=0.f,a3=0.f,a4=0.f,a5=0.f,a6=0.f,a7=0.f;
    float cnt = 0.f;

    if (row < B) {
        const int base = row * N + lane;
        const int   k      = kd[base];
        const float predl2 = logits[base] * LOG2E;

        // group-end lane e: smallest j >= lane with (j==63 or k[j]!=k[j+1])
        const int knext = __shfl_down(k, 1);
        unsigned long long endm = __ballot(lane == 63 || k != knext);
        const int e = lane + __builtin_ctzll(endm >> lane);  // bit63 set
        cnt = (float)(63 - e);

        #pragma unroll 1
        for (int bb = 0; bb < N; bb += 8) {
            TERM(0, a0); TERM(1, a1); TERM(2, a2); TERM(3, a3);
            TERM(4, a4); TERM(5, a5); TERM(6, a6); TERM(7, a7);
        }
    }

    float psum = ((a0 + a1) + (a2 + a3)) + ((a4 + a5) + (a6 + a7));
    #pragma unroll
    for (int off = 32; off; off >>= 1) {
        psum += __shfl_down(psum, off);
        cnt  += __shfl_down(cnt,  off);
    }

    __shared__ float ssum[WPB], scnt[WPB];
    if (lane == 0) { ssum[wave] = psum; scnt[wave] = cnt; }
    __syncthreads();
    if (threadIdx.x == 0) {
        float s = 0.f, c = 0.f;
        #pragma unroll
        for (int w = 0; w < WPB; ++w) { s += ssum[w]; c += scnt[w]; }
        partials[blockIdx.x] = make_float2(s, c);
    }
}

__global__ __launch_bounds__(256) void rank_loss_final(
    const float2* __restrict__ partials, float* __restrict__ out, int nPartials)
{
    const int t = threadIdx.x;
    float s = 0.f, c = 0.f;
    for (int i = t; i < nPartials; i += 256) {
        float2 p = partials[i];
        s += p.x; c += p.y;
    }
    #pragma unroll
    for (int off = 32; off; off >>= 1) {
        s += __shfl_down(s, off);
        c += __shfl_down(c, off);
    }
    __shared__ float ss[4], sc[4];
    const int lane = t & 63, wavei = t >> 6;
    if (lane == 0) { ss[wavei] = s; sc[wavei] = c; }
    __syncthreads();
    if (t == 0) {
        float S = 0.f, C = 0.f;
        #pragma unroll
        for (int w = 0; w < 4; ++w) { S += ss[w]; C += sc[w]; }
        out[0] = S * LN2 / C;
    }
}

extern "C" void kernel_launch(void* const* d_in, const int* in_sizes, int n_in,
                              void* d_out, int out_size, void* d_ws, size_t ws_size,
                              hipStream_t stream) {
    const float* logits = (const float*)d_in[0];
    const int*   kd     = (const int*)d_in[1];
    float*       out    = (float*)d_out;
    const int B = in_sizes[1] / N;              // 4096
    const int nBlocks = (B + WPB - 1) / WPB;    // 1024
    float2* partials = (float2*)d_ws;           // 8 KiB of ws

    rank_loss_partial<<<nBlocks, 256, 0, stream>>>(logits, kd, partials, B);
    rank_loss_final<<<1, 256, 0, stream>>>(partials, out, nBlocks);
}